// Round 2
// baseline (3429.521 us; speedup 1.0000x reference)
//
#include <hip/hip_runtime.h>
#include <math.h>

// Problem constants
#define BQ 64
#define NOBJ 5
#define CIN 3
#define IMG_H 64
#define IMG_W 96
#define OH 32
#define OW 48
#define OC 128
#define NPAIR 25
#define PP 4
#define CONV_OUT 32

// Tiling: 2 output rows per block -> 5 staged input rows, 30 KB LDS
#define TILE_OH 2
#define NTILES (OH / TILE_OH)           // 16
#define IN_ROWS (TILE_OH * 2 + 1)       // 5
#define LDS_STRIDE 100                  // >= IMG_W + 2 pad cols
#define LDS_ELEMS (NOBJ * CIN * IN_ROWS * LDS_STRIDE)   // 7500 floats = 30 KB

// S layout in workspace: [2][BQ][NPAIR][OC] floats = 1.6 MB
// S[src][b][i*5+j][oc] = sum over 32x48 positions of relu(convA(s_i)+convB(s_j)+bias)

__global__ __launch_bounds__(256, 4) void conv_pair_reduce(
    const float* __restrict__ state,
    const float* __restrict__ state_next,
    const float* __restrict__ conv_w,
    const float* __restrict__ conv_b,
    float* __restrict__ S)
{
    __shared__ float sIn[LDS_ELEMS];    // 30 KB; reused as reduction buffer later

    const int tid  = threadIdx.x;
    const int tile = blockIdx.x;   // 0..15
    const int b    = blockIdx.y;   // 0..63
    const int src  = blockIdx.z;   // 0..1

    const float* g = (src == 0 ? state : state_next)
                   + (size_t)b * NOBJ * CIN * IMG_H * IMG_W;

    const int r0 = tile * (TILE_OH * 2);  // first input row of this tile

    // ---- stage input rows for all 5 objects, 3 channels (zero-pad right & bottom) ----
    for (int idx = tid; idx < LDS_ELEMS; idx += 256) {
        int col   = idx % LDS_STRIDE;
        int r     = idx / LDS_STRIDE;       // (obj*3+ci)*IN_ROWS + lr
        int lr    = r % IN_ROWS;
        int oc_ci = r / IN_ROWS;            // obj*3+ci, 0..14
        int gr    = r0 + lr;
        float v = 0.f;
        if (col < IMG_W && gr < IMG_H)
            v = g[(size_t)oc_ci * (IMG_H * IMG_W) + gr * IMG_W + col];
        sIn[idx] = v;
    }

    // ---- per-thread weights: oc = tid & 127, grp = output row within tile ----
    const int oc  = tid & 127;
    const int grp = tid >> 7;   // 0 or 1: which of the 2 output rows
    float wA[27], wB[27];
    const float* wp = conv_w + oc * 54;   // conv_w[oc][6][3][3]
    #pragma unroll
    for (int k = 0; k < 27; ++k) { wA[k] = wp[k]; wB[k] = wp[27 + k]; }
    const float bias = conv_b[oc];

    __syncthreads();

    float acc[NPAIR];
    #pragma unroll
    for (int q = 0; q < NPAIR; ++q) acc[q] = 0.f;

    // SAME padding, stride 2: pad_lo=0, pad_hi=1 -> output (orow,ocol) reads
    // input rows orow*2..+2, cols ocol*2..+2. This thread: one output row.
    {
        const int lr0 = grp * 2;            // offset within the 5 staged rows
        for (int ocol = 0; ocol < OW; ++ocol) {
            const int lc0 = ocol * 2;
            float av[NOBJ], bv[NOBJ];
            #pragma unroll
            for (int obj = 0; obj < NOBJ; ++obj) {
                float sa = 0.f, sb = 0.f;
                #pragma unroll
                for (int ci = 0; ci < CIN; ++ci) {
                    #pragma unroll
                    for (int kh = 0; kh < 3; ++kh) {
                        const float* rp = &sIn[((obj * CIN + ci) * IN_ROWS + lr0 + kh) * LDS_STRIDE + lc0];
                        float x0 = rp[0], x1 = rp[1], x2 = rp[2];
                        const int wi = ci * 9 + kh * 3;
                        sa += x0 * wA[wi] + x1 * wA[wi + 1] + x2 * wA[wi + 2];
                        sb += x0 * wB[wi] + x1 * wB[wi + 1] + x2 * wB[wi + 2];
                    }
                }
                av[obj] = sa + bias;   // fold bias into A-half
                bv[obj] = sb;
            }
            #pragma unroll
            for (int i = 0; i < NOBJ; ++i) {
                #pragma unroll
                for (int j = 0; j < NOBJ; ++j) {
                    float v = av[i] + bv[j];
                    acc[i * NOBJ + j] += fmaxf(v, 0.f);
                }
            }
        }
    }

    // ---- block-level reduce (grp1 -> LDS, grp0 adds), then one atomic set ----
    __syncthreads();                 // done reading sIn as image data
    float* sRed = sIn;               // reuse: 128*25 floats = 12.8 KB
    if (grp == 1) {
        #pragma unroll
        for (int q = 0; q < NPAIR; ++q) sRed[oc * NPAIR + q] = acc[q];
    }
    __syncthreads();
    if (grp == 0) {
        float* sp = S + ((size_t)(src * BQ + b) * NPAIR) * OC + oc;
        #pragma unroll
        for (int q = 0; q < NPAIR; ++q)
            atomicAdd(&sp[q * OC], acc[q] + sRed[oc * NPAIR + q]);
    }
}

__global__ __launch_bounds__(256) void finalize_kernel(
    const float* __restrict__ S,
    const float* __restrict__ w2,
    const float* __restrict__ b2,
    const float* __restrict__ temp,
    float* __restrict__ out)
{
    int idx = blockIdx.x * blockDim.x + threadIdx.x;  // 0 .. 2*1600*4-1
    if (idx >= 2 * 1600 * PP) return;
    int p   = idx & 3;
    int t   = (idx >> 2) % 1600;
    int src = idx / (1600 * PP);
    const float* s = S + ((size_t)(src * 1600 + t)) * OC + p * CONV_OUT;
    float sum = 0.f;
    #pragma unroll
    for (int c = 0; c < CONV_OUT; ++c) sum += s[c] * w2[p * CONV_OUT + c];
    float logit = sum * (1.0f / (OH * OW)) + b2[p];
    float x = logit / temp[0];
    out[idx] = 1.0f / (1.0f + expf(-x));
}

__global__ __launch_bounds__(256) void adj_kernel(float* __restrict__ out)
{
    int idx = blockIdx.x * blockDim.x + threadIdx.x;
    if (idx >= BQ * 1600) return;
    int b = idx / 1600;
    int t = idx - b * 1600;
    out[idx] = (t / NPAIR == b) ? 1.0f : 0.0f;
}

extern "C" void kernel_launch(void* const* d_in, const int* in_sizes, int n_in,
                              void* d_out, int out_size, void* d_ws, size_t ws_size,
                              hipStream_t stream)
{
    const float* state      = (const float*)d_in[0];
    const float* state_next = (const float*)d_in[1];
    const float* conv_w     = (const float*)d_in[2];
    const float* conv_b     = (const float*)d_in[3];
    const float* w2         = (const float*)d_in[4];
    const float* b2         = (const float*)d_in[5];
    // d_in[6] = n_obj (unused: always 5)
    const float* temp       = (const float*)d_in[7];

    float* out = (float*)d_out;
    float* S   = (float*)d_ws;

    const size_t sbytes = (size_t)2 * BQ * NPAIR * OC * sizeof(float);
    hipMemsetAsync(S, 0, sbytes, stream);

    dim3 grid1(NTILES, BQ, 2);
    conv_pair_reduce<<<grid1, 256, 0, stream>>>(state, state_next, conv_w, conv_b, S);

    finalize_kernel<<<(2 * 1600 * PP + 255) / 256, 256, 0, stream>>>(S, w2, b2, temp, out);
    adj_kernel<<<(BQ * 1600 + 255) / 256, 256, 0, stream>>>(out + 2 * 1600 * PP);
}

// Round 3
// 201.632 us; speedup vs baseline: 17.0088x; 17.0088x over previous
//
#include <hip/hip_runtime.h>
#include <math.h>

// Problem constants
#define BQ 64
#define NOBJ 5
#define CIN 3
#define IMG_H 64
#define IMG_W 96
#define OH 32
#define OW 48
#define OC 128
#define NPAIR 25
#define PP 4
#define CONV_OUT 32

// Tiling: each block = (src, b, rowgroup of 2 output rows)
#define NRG 16                         // 32 output rows / 2
#define IN_ROWS 5                      // 2*2+1 input rows per rowgroup
#define LSTRIDE 98                     // shorts per staged row (needs 97)
#define NCH (NOBJ * CIN)               // 15
#define IMG_ELEMS (NCH * IN_ROWS * LSTRIDE)   // 7350 shorts = 14.7 KB
#define WELEMS (2 * OC * 32)           // 8192 shorts = 16 KB

typedef __attribute__((ext_vector_type(8))) short short8;
typedef __attribute__((ext_vector_type(4))) float float4_;

__device__ inline unsigned short f2bf(float f) {
    unsigned u = __builtin_bit_cast(unsigned, f);
    u += 0x7fff + ((u >> 16) & 1);          // round-to-nearest-even
    return (unsigned short)(u >> 16);
}

// T[src][b*25+pair][p] = sum over pos,oc of w2[p][oc%32]*relu(convA_i+convB_j+bias)
__global__ __launch_bounds__(256) void conv_pair_mfma(
    const float* __restrict__ state,
    const float* __restrict__ state_next,
    const float* __restrict__ conv_w,
    const float* __restrict__ conv_b,
    const float* __restrict__ w2,
    float* __restrict__ T)
{
    __shared__ __align__(16) unsigned short sImg[IMG_ELEMS];
    __shared__ __align__(16) unsigned short sW[WELEMS];

    const int tid = threadIdx.x;
    const int rg  = blockIdx.x;     // 0..15 (2 output rows each)
    const int b   = blockIdx.y;     // 0..63
    const int src = blockIdx.z;     // 0..1

    const float* g = (src == 0 ? state : state_next)
                   + (size_t)b * NCH * IMG_H * IMG_W;
    const int R0 = rg * 4;          // first input row

    // ---- stage image rows as bf16 (zero-pad right col 96 and bottom row) ----
    for (int idx = tid; idx < IMG_ELEMS; idx += 256) {
        int col  = idx % LSTRIDE;
        int rest = idx / LSTRIDE;
        int lr   = rest % IN_ROWS;
        int ch   = rest / IN_ROWS;          // obj*3+ci
        int gr   = R0 + lr;
        float v = 0.f;
        if (col < IMG_W && gr < IMG_H)
            v = g[ch * (IMG_H * IMG_W) + gr * IMG_W + col];
        sImg[idx] = f2bf(v);
    }
    // ---- stage weights: sW[half][oc][k32]; k==27 on A-half carries the bias ----
    for (int idx = tid; idx < WELEMS; idx += 256) {
        int k    = idx & 31;
        int oc   = (idx >> 5) & (OC - 1);
        int half = idx >> 12;
        float v = 0.f;
        if (k < 27)                        v = conv_w[oc * 54 + half * 27 + k];
        else if (k == 27 && half == 0)     v = conv_b[oc];
        sW[idx] = f2bf(v);
    }
    __syncthreads();

    const int wave = tid >> 6;
    const int lane = tid & 63;
    const int quad = lane >> 4;
    const int ocl  = lane & 15;

    // per-lane im2col offsets for this lane's 8 k-values (k = quad*8+j)
    int koff[8];
    #pragma unroll
    for (int j = 0; j < 8; ++j) {
        int k  = quad * 8 + j;
        int kk = (k > 26) ? 0 : k;          // clamp padding k to stay in-bounds
        int ci = kk / 9;
        int rem = kk - ci * 9;
        int kh = rem / 3;
        int kw = rem - kh * 3;
        koff[j] = (ci * IN_ROWS + kh) * LSTRIDE + kw;
    }

    const float4_ zero4 = {0.f, 0.f, 0.f, 0.f};

    #pragma unroll
    for (int pass = 0; pass < 2; ++pass) {
        const int mt = wave + pass * 4;     // M-tile (16 oc) 0..7
        const int p  = mt >> 1;             // predicate group

        short8 wa = *(const short8*)&sW[(size_t)((0 * OC + mt * 16 + ocl) * 32 + quad * 8)];
        short8 wb = *(const short8*)&sW[(size_t)((1 * OC + mt * 16 + ocl) * 32 + quad * 8)];
        float w2v[4];
        #pragma unroll
        for (int r = 0; r < 4; ++r)
            w2v[r] = w2[p * CONV_OUT + (((mt & 1) * 16 + quad * 4 + r) & 31)];

        float acc[NPAIR];
        #pragma unroll
        for (int q = 0; q < NPAIR; ++q) acc[q] = 0.f;

        for (int nt = 0; nt < 6; ++nt) {    // 2 rows x 3 col-tiles of 16
            const int rl = nt / 3;
            const int c0 = (nt - rl * 3) * 16;
            const int base = (2 * rl) * LSTRIDE + 2 * (c0 + ocl);

            float4_ av[NOBJ], bv[NOBJ];
            #pragma unroll
            for (int obj = 0; obj < NOBJ; ++obj) {
                const int ob = obj * (CIN * IN_ROWS) * LSTRIDE + base;
                short8 xf;
                #pragma unroll
                for (int j = 0; j < 8; ++j)
                    xf[j] = (short)sImg[ob + koff[j]];
                if (quad == 3) {            // k=27 -> 1.0 (bias lane), k>27 -> 0
                    xf[3] = (short)0x3f80;
                    xf[4] = 0; xf[5] = 0; xf[6] = 0; xf[7] = 0;
                }
                av[obj] = __builtin_amdgcn_mfma_f32_16x16x32_bf16(wa, xf, zero4, 0, 0, 0);
                bv[obj] = __builtin_amdgcn_mfma_f32_16x16x32_bf16(wb, xf, zero4, 0, 0, 0);
            }

            #pragma unroll
            for (int i = 0; i < NOBJ; ++i) {
                #pragma unroll
                for (int j = 0; j < NOBJ; ++j) {
                    float s = 0.f;
                    #pragma unroll
                    for (int r = 0; r < 4; ++r) {
                        float v = av[i][r] + bv[j][r];
                        v = fmaxf(v, 0.f);
                        s = fmaf(w2v[r], v, s);
                    }
                    acc[i * NOBJ + j] += s;
                }
            }
        }

        // ---- wave-reduce each pair sum across 64 lanes, then 25 atomics ----
        float myv = 0.f;
        #pragma unroll
        for (int q = 0; q < NPAIR; ++q) {
            float r = acc[q];
            #pragma unroll
            for (int off = 32; off > 0; off >>= 1)
                r += __shfl_xor(r, off, 64);
            if (lane == q) myv = r;
        }
        if (lane < NPAIR)
            atomicAdd(&T[((size_t)src * 1600 + b * NPAIR + lane) * PP + p], myv);
    }
}

__global__ __launch_bounds__(256) void finalize_kernel(
    const float* __restrict__ T,
    const float* __restrict__ b2,
    const float* __restrict__ temp,
    float* __restrict__ out)
{
    int idx = blockIdx.x * blockDim.x + threadIdx.x;   // 0 .. 2*1600*4-1
    if (idx >= 2 * 1600 * PP) return;
    int p = idx & 3;
    float logit = T[idx] * (1.0f / (OH * OW)) + b2[p];
    float x = logit / temp[0];
    out[idx] = 1.0f / (1.0f + expf(-x));
}

__global__ __launch_bounds__(256) void adj_kernel(float* __restrict__ out)
{
    int idx = blockIdx.x * blockDim.x + threadIdx.x;
    if (idx >= BQ * 1600) return;
    int b = idx / 1600;
    int t = idx - b * 1600;
    out[idx] = (t / NPAIR == b) ? 1.0f : 0.0f;
}

extern "C" void kernel_launch(void* const* d_in, const int* in_sizes, int n_in,
                              void* d_out, int out_size, void* d_ws, size_t ws_size,
                              hipStream_t stream)
{
    const float* state      = (const float*)d_in[0];
    const float* state_next = (const float*)d_in[1];
    const float* conv_w     = (const float*)d_in[2];
    const float* conv_b     = (const float*)d_in[3];
    const float* w2         = (const float*)d_in[4];
    const float* b2         = (const float*)d_in[5];
    // d_in[6] = n_obj (always 5)
    const float* temp       = (const float*)d_in[7];

    float* out = (float*)d_out;
    float* T   = (float*)d_ws;              // [2][1600][4] floats = 51.2 KB

    hipMemsetAsync(T, 0, (size_t)2 * 1600 * PP * sizeof(float), stream);

    dim3 grid1(NRG, BQ, 2);                 // 2048 blocks
    conv_pair_mfma<<<grid1, 256, 0, stream>>>(state, state_next, conv_w, conv_b, w2, T);

    finalize_kernel<<<(2 * 1600 * PP + 255) / 256, 256, 0, stream>>>(T, b2, temp, out);
    adj_kernel<<<(BQ * 1600 + 255) / 256, 256, 0, stream>>>(out + 2 * 1600 * PP);
}